// Round 13
// baseline (10723.421 us; speedup 1.0000x reference)
//
#include <hip/hip_runtime.h>
#include <hip/hip_bf16.h>

// LSTM: B=1024, T=512, I=64, H=256, O=1
// Round 13 = round-12 resubmit (acquisition timeout; never ran).
// Register-resident W_hh via hidden-split WG pairs.
// Measured: r1 stream-from-L2 7131us (latency-bound, 64 CUs); r5 single-WG
// full-residency spilled (cap 128 < demand 270) 8790us; r11 source staging
// pipeline collapsed by compiler (VGPR=128) 8305us.
// => weights must be loop-invariant registers under a cap >= demand, and
// more CUs must work. Pair design: 256KB W_hh-half per CU, ~250 VGPR/lane
// at launch_bounds(512,2) (cap 256); weights loaded ONCE outside the t-loop.
//  grid = 128 WGs x 512 thr. Pair (g, g+64) owns batch rows [16g,16g+16)
//  (same blockIdx%8 -> same XCD -> handshake in shared per-XCD L2).
//  WG half s owns hidden cols [128s,128s+128): all 4 gates for those cols ->
//  nonlinearity + c update wave-local. Per wave: 16 hidden cols; W_hh slice
//  4 gates x 8 kfrags = 128 VGPR bf16, W_ih 32 VGPR.
//  Per step: exchange 4KB h-half via global double buffer + acq/rel counters
//  (agent scope). PER-WAVE acquire spin (uniform-address poll) -> only 2
//  barriers/step. Own half via swizzled LDS.
//  Co-residency: 1 WG/CU (VGPR-limited), 128 WGs <= CU count (checked on
//  host; falls back if < 128 CUs) -> all resident; spin cannot deadlock.
//  init_kernel re-inits out+cnt inside the graph -> replay-safe.

typedef float f32x4 __attribute__((ext_vector_type(4)));
typedef short s16x8 __attribute__((ext_vector_type(8)));

#define BB 1024
#define TT 512
#define II 64
#define HH 256
#define GG 1024  // 4*H

__device__ __forceinline__ ushort f2bf(float f) {
  unsigned u = __builtin_bit_cast(unsigned, f);
  u = (u + 0x7FFFu + ((u >> 16) & 1u)) >> 16;  // RNE
  return (ushort)u;
}

__device__ __forceinline__ float sigm(float x) {
  return 1.0f / (1.0f + __expf(-x));
}
__device__ __forceinline__ float tanh_s(float x) {
  float e = __expf(-2.0f * fabsf(x));
  float t = (1.0f - e) / (1.0f + e);
  return copysignf(t, x);
}

__device__ __forceinline__ s16x8 pack_bf8(const float* p) {
  f32x4 a = *(const f32x4*)p;
  f32x4 b = *(const f32x4*)(p + 4);
  s16x8 r;
  r[0] = (short)f2bf(a[0]); r[1] = (short)f2bf(a[1]);
  r[2] = (short)f2bf(a[2]); r[3] = (short)f2bf(a[3]);
  r[4] = (short)f2bf(b[0]); r[5] = (short)f2bf(b[1]);
  r[6] = (short)f2bf(b[2]); r[7] = (short)f2bf(b[3]);
  return r;
}

__global__ void init_kernel(float* __restrict__ out, unsigned* __restrict__ cnt) {
  int i = blockIdx.x * 256 + threadIdx.x;
  if (i < 1024) out[i] = 0.0f;
  if (i < 2048) cnt[i] = 0u;  // ws re-poisoned to 0xAA before every launch
}

__global__ __launch_bounds__(512, 2) void lstm_pair(
    const float* __restrict__ x,      // [B,T,I]
    const float* __restrict__ wih_f,  // [4H,I]
    const float* __restrict__ whh_f,  // [4H,H]
    const float* __restrict__ b_ih,   // [4H]
    const float* __restrict__ b_hh,   // [4H]
    const float* __restrict__ w_out,  // [1,H]
    const float* __restrict__ b_out,  // [1]
    unsigned* __restrict__ cnt,       // flags: 2048 u32 (64B padded per WG)
    ushort* __restrict__ hx,          // [2][64][16][256] bf16 h exchange
    float* __restrict__ out)          // [B]
{
  __shared__ ushort h_lds[16 * 128];  // own half, XOR-swizzled bf16
  __shared__ float hf[16][128];       // final h (own half), fp32

  const int tid  = threadIdx.x;
  const int wv   = tid >> 6;
  const int l    = tid & 63;
  const int lrow = l & 15;
  const int lk8  = (l >> 4) << 3;
  const int crow = (l >> 4) << 2;
  const int ccol = l & 15;
  const int grp  = blockIdx.x & 63;   // batch group: pair = (g, g+64)
  const int half = blockIdx.x >> 6;   // hidden half; same blockIdx%8 per pair
  const int b0   = grp << 4;
  const int lc   = (wv << 4) + ccol;  // local hidden col 0..127
  const int hc0  = half << 7;         // global col base of own half

  // ---- load weights into registers once (fp32 -> bf16), loop-invariant ----
  s16x8 whh[4][8];  // [gate][kfrag], k global = kf*32 + lk8
  s16x8 wih[4][2];
  float bs[4];
#pragma unroll
  for (int g = 0; g < 4; ++g) {
    const int wrow = g * 256 + hc0 + (wv << 4) + lrow;
#pragma unroll
    for (int kf = 0; kf < 8; ++kf)
      whh[g][kf] = pack_bf8(whh_f + wrow * HH + kf * 32 + lk8);
#pragma unroll
    for (int kf = 0; kf < 2; ++kf)
      wih[g][kf] = pack_bf8(wih_f + wrow * II + kf * 32 + lk8);
    const int c = g * 256 + hc0 + (wv << 4) + ccol;
    bs[g] = b_ih[c] + b_hh[c];
  }

  float cst[4] = {0.f, 0.f, 0.f, 0.f};

  unsigned* mycnt = cnt + (((grp << 1) + half) << 4);
  unsigned* pcnt  = cnt + (((grp << 1) + (1 - half)) << 4);

  // x fragments for t=0
  s16x8 xf[2];
  {
    const float* xp = x + ((size_t)(b0 + lrow) * TT) * II + lk8;
    xf[0] = pack_bf8(xp);
    xf[1] = pack_bf8(xp + 32);
  }

  for (int t = 0; t < TT; ++t) {
    s16x8 hown[4], hrem[4];
    if (t > 0) {
      // per-wave acquire: all lanes poll the uniform flag address; each wave
      // proceeds independently once the partner's release for step t lands.
      while (__hip_atomic_load(pcnt, __ATOMIC_ACQUIRE,
                               __HIP_MEMORY_SCOPE_AGENT) < (unsigned)t)
        __builtin_amdgcn_s_sleep(1);
      // remote half from global (issue early - long pole)
      const ushort* rb = hx + ((size_t)(((t & 1) * 64 + grp) * 16 + lrow)) * 256
                         + (1 - half) * 128 + lk8;
#pragma unroll
      for (int kf = 0; kf < 4; ++kf)
        hrem[kf] = *(const s16x8*)(rb + kf * 32);
      // own half from LDS (swizzled); ordered vs last step's writes by the
      // end-of-step barrier of step t-1.
#pragma unroll
      for (int kf = 0; kf < 4; ++kf) {
        int byte = (lrow * 256 + (kf * 32 + lk8) * 2) ^ ((lrow & 7) << 4);
        hown[kf] = *(const s16x8*)((const char*)h_lds + byte);
      }
    }

    // prefetch x for t+1 (hides HBM latency under MFMA)
    s16x8 xfn[2];
    if (t < TT - 1) {
      const float* xp = x + ((size_t)(b0 + lrow) * TT + (t + 1)) * II + lk8;
      xfn[0] = pack_bf8(xp);
      xfn[1] = pack_bf8(xp + 32);
    }

    f32x4 acc[4];
#pragma unroll
    for (int g = 0; g < 4; ++g) {
      f32x4 a;
      a[0] = a[1] = a[2] = a[3] = bs[g];
      a = __builtin_amdgcn_mfma_f32_16x16x32_bf16(xf[0], wih[g][0], a, 0, 0, 0);
      a = __builtin_amdgcn_mfma_f32_16x16x32_bf16(xf[1], wih[g][1], a, 0, 0, 0);
      if (t > 0) {
#pragma unroll
        for (int kf = 0; kf < 4; ++kf)  // own half first (LDS, fast)
          a = __builtin_amdgcn_mfma_f32_16x16x32_bf16(hown[kf],
                whh[g][half * 4 + kf], a, 0, 0, 0);
#pragma unroll
        for (int kf = 0; kf < 4; ++kf)  // remote half
          a = __builtin_amdgcn_mfma_f32_16x16x32_bf16(hrem[kf],
                whh[g][(1 - half) * 4 + kf], a, 0, 0, 0);
      }
      acc[g] = a;
    }

    if (t > 0) __syncthreads();  // all h_t reads done before h_{t+1} LDS writes

    // nonlinearity + state update + h writes
#pragma unroll
    for (int r = 0; r < 4; ++r) {
      float gi = sigm(acc[0][r]);
      float gf = sigm(acc[1][r]);
      float gg = tanh_s(acc[2][r]);
      float go = sigm(acc[3][r]);
      float cn = gf * cst[r] + gi * gg;
      cst[r] = cn;
      float hn = go * tanh_s(cn);
      int row = crow + r;
      if (t == TT - 1) {
        hf[row][lc] = hn;
      } else {
        ushort hb = f2bf(hn);
        int byte = (row * 256 + lc * 2) ^ ((row & 7) << 4);
        *(ushort*)((char*)h_lds + byte) = hb;
        hx[((size_t)((((t + 1) & 1) * 64 + grp) * 16 + row)) * 256 + hc0 + lc] = hb;
      }
    }

    if (t < TT - 1) {
      __syncthreads();  // per-wave vmcnt drained at barrier -> hx stores done
      if (tid == 0)
        __hip_atomic_store(mycnt, (unsigned)(t + 1), __ATOMIC_RELEASE,
                           __HIP_MEMORY_SCOPE_AGENT);
    }
    xf[0] = xfn[0];
    xf[1] = xfn[1];
  }

  __syncthreads();
  // epilogue: out[b] += h_half . w_out_half (+ b_out from half 0)
  {
    const int row = wv << 1;
#pragma unroll
    for (int rr = 0; rr < 2; ++rr) {
      float s = hf[row + rr][l] * w_out[hc0 + l] +
                hf[row + rr][l + 64] * w_out[hc0 + l + 64];
#pragma unroll
      for (int off = 32; off >= 1; off >>= 1) s += __shfl_xor(s, off);
      if (l == 0)
        atomicAdd(out + b0 + row + rr, s + (half == 0 ? b_out[0] : 0.f));
    }
  }
}

// ---------------- fallback (round-1 kernel; used only if <128 CUs or tiny ws) ----
__global__ __launch_bounds__(512, 2) void lstm_fallback(
    const float* __restrict__ x, const float* __restrict__ wih_f,
    const float* __restrict__ whh_f, const float* __restrict__ b_ih,
    const float* __restrict__ b_hh, const float* __restrict__ w_out,
    const float* __restrict__ b_out, float* __restrict__ out) {
  __shared__ ushort h_lds[16 * 256];
  __shared__ float hf[16][256];
  const int tid = threadIdx.x, wv = tid >> 6, l = tid & 63;
  const int lrow = l & 15, lk8 = (l >> 4) << 3, crow = (l >> 4) << 2, ccol = l & 15;
  const int b0 = blockIdx.x << 4, jw = wv << 5;
  { s16x8 z = {}; *(s16x8*)&h_lds[tid * 8] = z; }
  s16x8 wihf[4][2][2];
#pragma unroll
  for (int g = 0; g < 4; ++g)
#pragma unroll
    for (int nt = 0; nt < 2; ++nt)
#pragma unroll
      for (int kt = 0; kt < 2; ++kt)
        wihf[g][nt][kt] = pack_bf8(wih_f + (g * 256 + jw + nt * 16 + lrow) * II + kt * 32 + lk8);
  float bs[4][2];
#pragma unroll
  for (int g = 0; g < 4; ++g)
#pragma unroll
    for (int nt = 0; nt < 2; ++nt) {
      int c = g * 256 + jw + nt * 16 + ccol;
      bs[g][nt] = b_ih[c] + b_hh[c];
    }
  float cst[2][4] = {};
  __syncthreads();
  for (int t = 0; t < TT; ++t) {
    s16x8 xf[2];
    {
      const float* xp = x + ((size_t)(b0 + lrow) * TT + t) * II + lk8;
      xf[0] = pack_bf8(xp); xf[1] = pack_bf8(xp + 32);
    }
    s16x8 hfr[8];
#pragma unroll
    for (int kt = 0; kt < 8; ++kt) {
      int byte = (lrow * 512 + (kt * 32 + lk8) * 2) ^ ((lrow & 7) << 4);
      hfr[kt] = *(const s16x8*)((const char*)h_lds + byte);
    }
    f32x4 acc[4][2];
#pragma unroll
    for (int g = 0; g < 4; ++g)
#pragma unroll
      for (int nt = 0; nt < 2; ++nt) {
        f32x4 a; a[0] = a[1] = a[2] = a[3] = bs[g][nt];
        s16x8 bw[8];
        int jrow = g * 256 + jw + nt * 16 + lrow;
#pragma unroll
        for (int kt = 0; kt < 8; ++kt)
          bw[kt] = pack_bf8(whh_f + jrow * HH + kt * 32 + lk8);
        a = __builtin_amdgcn_mfma_f32_16x16x32_bf16(xf[0], wihf[g][nt][0], a, 0, 0, 0);
        a = __builtin_amdgcn_mfma_f32_16x16x32_bf16(xf[1], wihf[g][nt][1], a, 0, 0, 0);
#pragma unroll
        for (int kt = 0; kt < 8; ++kt)
          a = __builtin_amdgcn_mfma_f32_16x16x32_bf16(hfr[kt], bw[kt], a, 0, 0, 0);
        acc[g][nt] = a;
      }
    __syncthreads();
#pragma unroll
    for (int nt = 0; nt < 2; ++nt)
#pragma unroll
      for (int r = 0; r < 4; ++r) {
        float gi = sigm(acc[0][nt][r]), gf = sigm(acc[1][nt][r]);
        float gg = tanh_s(acc[2][nt][r]), go = sigm(acc[3][nt][r]);
        float cn = gf * cst[nt][r] + gi * gg;
        cst[nt][r] = cn;
        float hn = go * tanh_s(cn);
        int row = crow + r, col = jw + nt * 16 + ccol;
        int byte = (row * 512 + col * 2) ^ ((row & 7) << 4);
        *(ushort*)((char*)h_lds + byte) = f2bf(hn);
        if (t == TT - 1) hf[row][col] = hn;
      }
    __syncthreads();
  }
#pragma unroll
  for (int rr = 0; rr < 2; ++rr) {
    int row = wv * 2 + rr;
    float s = 0.f;
#pragma unroll
    for (int m = 0; m < 4; ++m) s += hf[row][l + 64 * m] * w_out[l + 64 * m];
#pragma unroll
    for (int off = 32; off >= 1; off >>= 1) s += __shfl_xor(s, off);
    if (l == 0) out[b0 + row] = s + b_out[0];
  }
}

extern "C" void kernel_launch(void* const* d_in, const int* in_sizes, int n_in,
                              void* d_out, int out_size, void* d_ws, size_t ws_size,
                              hipStream_t stream) {
  const float* x     = (const float*)d_in[0];
  const float* wih   = (const float*)d_in[1];
  const float* whh   = (const float*)d_in[2];
  const float* b_ih  = (const float*)d_in[3];
  const float* b_hh  = (const float*)d_in[4];
  const float* w_out = (const float*)d_in[5];
  const float* b_out = (const float*)d_in[6];
  float* out = (float*)d_out;

  // capture-safe device query: pair design needs 128 co-resident WGs (1/CU)
  int dev = 0, nCU = 0;
  hipGetDevice(&dev);
  hipDeviceGetAttribute(&nCU, hipDeviceAttributeMultiprocessorCount, dev);

  // ws layout: [0,8KB) counters ; [8KB, 8KB+1MB) h exchange buffers
  const size_t ws_needed = 8192 + (size_t)2 * 64 * 16 * 256 * sizeof(ushort);
  if (ws_size >= ws_needed && nCU >= 128) {
    unsigned* cnt = (unsigned*)d_ws;
    ushort* hx = (ushort*)((char*)d_ws + 8192);
    init_kernel<<<8, 256, 0, stream>>>(out, cnt);
    lstm_pair<<<128, 512, 0, stream>>>(x, wih, whh, b_ih, b_hh, w_out, b_out,
                                       cnt, hx, out);
  } else {
    lstm_fallback<<<64, 512, 0, stream>>>(x, wih, whh, b_ih, b_hh, w_out, b_out,
                                          out);
  }
}